// Round 4
// baseline (3849.899 us; speedup 1.0000x reference)
//
#include <hip/hip_runtime.h>
#include <stdint.h>

// ---------------------------------------------------------------------------
// GatedLinearAttention (b=4, T=2048, D=2048, H=8, dk=128, dv=256, CHUNK=128)
// Precision-first round: hi/lo bf16-pair projection GEMMs (fp32-grade inputs),
// QK stored fp32, fused gk+scan+LayerNorm+gate keeping o fp32 end-to-end.
//
// ws layout (112.5 MiB; round-2 guard proved ws >= 120.75 MiB):
//   QK f32 [0,64Mi)      [q | k/16] fp32 [8192][2048]; reused as final-C
//   V bf16 [64Mi,96Mi)   v [8192][2048]
//   WtA    [96Mi,104Mi)  weight^T hi-plane bf16 2048x2048 (reused serially)
//   WtB    [104Mi,112Mi) weight^T lo-plane
//   xg1    [112Mi,+512K) x@Wkg1 fp32
// d_out scratch: G bf16 [0,32Mi), OG bf16 [32Mi,64Mi); final C copied in last.
// ---------------------------------------------------------------------------

typedef unsigned short u16;
typedef unsigned int u32;
typedef __bf16 bf16x8 __attribute__((ext_vector_type(8)));
typedef float f32x4 __attribute__((ext_vector_type(4)));

__device__ __forceinline__ u16 f2bf(float f) {
  u32 u = __float_as_uint(f);
  u32 r = (u + 0x7fffu + ((u >> 16) & 1u)) >> 16;   // RNE
  return (u16)r;
}
__device__ __forceinline__ float bf2f(u16 s) {
  return __uint_as_float(((u32)s) << 16);
}

// async global->LDS, 16B/lane. LDS dest = wave-uniform base + lane*16.
__device__ __forceinline__ void load_lds16(const void* g, void* l) {
  auto gp = (const __attribute__((address_space(1))) u32*)(uintptr_t)g;
  auto lp = (__attribute__((address_space(3))) u32*)(u32)(uintptr_t)l;
  __builtin_amdgcn_global_load_lds(gp, lp, 16, 0, 0);
}
__device__ __forceinline__ bf16x8 ldf(const u16* p) { return *(const bf16x8*)p; }

// ---------------------------------------------------------------------------
// weight transpose + hi/lo bf16 split: for n,k: v = src[k][n]*scale;
// hi = bf16(v), lo = bf16(v - hi).
__global__ __launch_bounds__(256) void tpose_pair(const float* __restrict__ src,
                                                  u16* __restrict__ dhi,
                                                  u16* __restrict__ dlo,
                                                  int srcRows, int srcStride,
                                                  float scale) {
  __shared__ float tile[32][33];
  const int tx = threadIdx.x, ty = threadIdx.y;     // block (32,8)
  const int n0 = blockIdx.x * 32, k0 = blockIdx.y * 32;
#pragma unroll
  for (int j = 0; j < 4; ++j) {
    int k = k0 + ty + j * 8;
    tile[ty + j * 8][tx] = src[(size_t)k * srcStride + n0 + tx] * scale;
  }
  __syncthreads();
#pragma unroll
  for (int j = 0; j < 4; ++j) {
    int n = n0 + ty + j * 8;
    float f = tile[tx][ty + j * 8];
    u16 h = f2bf(f);
    size_t idx = (size_t)n * srcRows + k0 + tx;
    dhi[idx] = h;
    dlo[idx] = f2bf(f - bf2f(h));
  }
}

// ---------------------------------------------------------------------------
// Pair GEMM: C[M,N] = A_f32[M,K] @ (Bhi+Blo)[N,K]^T with in-kernel A hi/lo
// split. COMBOS=3: hh+hl+lh (fp32-grade); COMBOS=1: hh only (plain bf16).
// OUTF32: 1 -> fp32 C, 0 -> bf16 C. 128x128 tile, BK=32.
template <int COMBOS, int OUTF32>
__global__ __launch_bounds__(256) void gemm_f32a(const float* __restrict__ A,
                                                 const u16* __restrict__ Bhi,
                                                 const u16* __restrict__ Blo,
                                                 void* __restrict__ C,
                                                 int M, int N, int K) {
  __shared__ u16 Ah[128 * 32];
  __shared__ u16 Al[128 * 32];
  __shared__ u16 Bh[128 * 32];
  __shared__ u16 Bl[128 * 32];
  const int tid = threadIdx.x;
  const int wave = tid >> 6, lane = tid & 63;
  const int wm = wave >> 1, wn = wave & 1;
  const int qu = lane >> 4, ln = lane & 15;
  const int m0 = blockIdx.y * 128, n0 = blockIdx.x * 128;
  const int arow = tid >> 1, akof = (tid & 1) << 4;   // 16 fp32 per thread
  const int crow = tid >> 2, ckof = (tid & 3) << 3;
  f32x4 acc[4][4] = {};
  for (int kt = 0; kt < K; kt += 32) {
    // B: async staging (hi, and lo if used)
#pragma unroll
    for (int r = 0; r < 2; ++r) {
      const int row = crow + r * 64;
      load_lds16(Bhi + (size_t)(n0 + row) * K + kt + ckof, Bh + (size_t)(r * 256 + wave * 64) * 8);
      if (COMBOS == 3)
        load_lds16(Blo + (size_t)(n0 + row) * K + kt + ckof, Bl + (size_t)(r * 256 + wave * 64) * 8);
    }
    // A: fp32 load -> hi/lo split -> LDS
    {
      const float* src = A + (size_t)(m0 + arow) * K + kt + akof;
      float va[16];
#pragma unroll
      for (int j = 0; j < 16; j += 4) {
        float4 f4 = *(const float4*)(src + j);
        va[j] = f4.x; va[j + 1] = f4.y; va[j + 2] = f4.z; va[j + 3] = f4.w;
      }
      u16 hi[16], lo[16];
#pragma unroll
      for (int j = 0; j < 16; ++j) {
        hi[j] = f2bf(va[j]);
        lo[j] = f2bf(va[j] - bf2f(hi[j]));
      }
      u32 ph[8];
#pragma unroll
      for (int j = 0; j < 8; ++j) ph[j] = (u32)hi[2 * j] | ((u32)hi[2 * j + 1] << 16);
      *(uint4*)&Ah[arow * 32 + akof] = make_uint4(ph[0], ph[1], ph[2], ph[3]);
      *(uint4*)&Ah[arow * 32 + akof + 8] = make_uint4(ph[4], ph[5], ph[6], ph[7]);
      if (COMBOS == 3) {
#pragma unroll
        for (int j = 0; j < 8; ++j) ph[j] = (u32)lo[2 * j] | ((u32)lo[2 * j + 1] << 16);
        *(uint4*)&Al[arow * 32 + akof] = make_uint4(ph[0], ph[1], ph[2], ph[3]);
        *(uint4*)&Al[arow * 32 + akof + 8] = make_uint4(ph[4], ph[5], ph[6], ph[7]);
      }
    }
    __syncthreads();
    bf16x8 ah[4], bh[4], al[4], bl[4];
#pragma unroll
    for (int t = 0; t < 4; ++t) {
      ah[t] = ldf(&Ah[(wm * 64 + t * 16 + ln) * 32 + qu * 8]);
      bh[t] = ldf(&Bh[(wn * 64 + t * 16 + ln) * 32 + qu * 8]);
      if (COMBOS == 3) {
        al[t] = ldf(&Al[(wm * 64 + t * 16 + ln) * 32 + qu * 8]);
        bl[t] = ldf(&Bl[(wn * 64 + t * 16 + ln) * 32 + qu * 8]);
      }
    }
#pragma unroll
    for (int ti = 0; ti < 4; ++ti)
#pragma unroll
      for (int tj = 0; tj < 4; ++tj) {
        acc[ti][tj] = __builtin_amdgcn_mfma_f32_16x16x32_bf16(ah[ti], bh[tj], acc[ti][tj], 0, 0, 0);
        if (COMBOS == 3) {
          acc[ti][tj] = __builtin_amdgcn_mfma_f32_16x16x32_bf16(ah[ti], bl[tj], acc[ti][tj], 0, 0, 0);
          acc[ti][tj] = __builtin_amdgcn_mfma_f32_16x16x32_bf16(al[ti], bh[tj], acc[ti][tj], 0, 0, 0);
        }
      }
    __syncthreads();
  }
#pragma unroll
  for (int ti = 0; ti < 4; ++ti)
#pragma unroll
    for (int tj = 0; tj < 4; ++tj) {
      const int rowb = m0 + wm * 64 + ti * 16 + qu * 4;   // C/D: row=(lane>>4)*4+reg
      const int col = n0 + wn * 64 + tj * 16 + ln;        //      col=lane&15
#pragma unroll
      for (int r = 0; r < 4; ++r) {
        size_t idx = (size_t)(rowb + r) * N + col;
        if (OUTF32) ((float*)C)[idx] = acc[ti][tj][r];
        else        ((u16*)C)[idx] = f2bf(acc[ti][tj][r]);
      }
    }
}

// ---------------------------------------------------------------------------
// Plain bf16-A GEMM (final projection): C_f32[M,N] = A_bf16 @ Bt^T.
__global__ __launch_bounds__(256) void gemm_bt(const u16* __restrict__ A,
                                               const u16* __restrict__ Bt,
                                               float* __restrict__ C,
                                               int M, int N, int K) {
  __shared__ u16 As[128 * 32];
  __shared__ u16 Bs[128 * 32];
  const int tid = threadIdx.x;
  const int wave = tid >> 6, lane = tid & 63;
  const int wm = wave >> 1, wn = wave & 1;
  const int qu = lane >> 4, ln = lane & 15;
  const int m0 = blockIdx.y * 128, n0 = blockIdx.x * 128;
  const int crow = tid >> 2, ckof = (tid & 3) << 3;
  f32x4 acc[4][4] = {};
  for (int kt = 0; kt < K; kt += 32) {
#pragma unroll
    for (int r = 0; r < 2; ++r) {
      const int row = crow + r * 64;
      load_lds16(A + (size_t)(m0 + row) * K + kt + ckof, As + (size_t)(r * 256 + wave * 64) * 8);
      load_lds16(Bt + (size_t)(n0 + row) * K + kt + ckof, Bs + (size_t)(r * 256 + wave * 64) * 8);
    }
    __syncthreads();
    bf16x8 af[4], bfr[4];
#pragma unroll
    for (int t = 0; t < 4; ++t) {
      af[t] = ldf(&As[(wm * 64 + t * 16 + ln) * 32 + qu * 8]);
      bfr[t] = ldf(&Bs[(wn * 64 + t * 16 + ln) * 32 + qu * 8]);
    }
#pragma unroll
    for (int ti = 0; ti < 4; ++ti)
#pragma unroll
      for (int tj = 0; tj < 4; ++tj)
        acc[ti][tj] = __builtin_amdgcn_mfma_f32_16x16x32_bf16(af[ti], bfr[tj], acc[ti][tj], 0, 0, 0);
    __syncthreads();
  }
#pragma unroll
  for (int ti = 0; ti < 4; ++ti)
#pragma unroll
    for (int tj = 0; tj < 4; ++tj) {
      const int rowb = m0 + wm * 64 + ti * 16 + qu * 4;
      const int col = n0 + wn * 64 + tj * 16 + ln;
#pragma unroll
      for (int r = 0; r < 4; ++r)
        C[(size_t)(rowb + r) * N + col] = acc[ti][tj][r];
    }
}

// ---------------------------------------------------------------------------
// xg1[8192,16] = x[8192,2048] @ Wkg1[2048,16]   (fp32, tiled)
__global__ __launch_bounds__(256) void xg1_gemm(const float* __restrict__ x,
                                                const float* __restrict__ W1,
                                                float* __restrict__ xg1) {
  __shared__ float xs[64][40];   // 160 B row stride: float4-aligned
  __shared__ float ws2[32][16];
  const int tid = threadIdx.x;
  const int r0 = blockIdx.x * 64;
  const int col = tid & 15, rsub = tid >> 4;
  float acc[4] = {0.f, 0.f, 0.f, 0.f};
  for (int kt = 0; kt < 2048; kt += 32) {
#pragma unroll
    for (int j = 0; j < 2; ++j) {
      int c = j * 256 + tid;
      int row = c >> 3, kk = (c & 7) << 2;
      *(float4*)&xs[row][kk] = *(const float4*)&x[(size_t)(r0 + row) * 2048 + kt + kk];
    }
#pragma unroll
    for (int j = 0; j < 2; ++j) {
      int c = j * 256 + tid;
      ws2[c >> 4][c & 15] = W1[(size_t)(kt + (c >> 4)) * 16 + (c & 15)];
    }
    __syncthreads();
#pragma unroll
    for (int kk = 0; kk < 32; ++kk) {
      float wv = ws2[kk][col];
#pragma unroll
      for (int j = 0; j < 4; ++j) acc[j] += xs[rsub + j * 16][kk] * wv;
    }
    __syncthreads();
  }
#pragma unroll
  for (int j = 0; j < 4; ++j) xg1[(size_t)(r0 + rsub + j * 16) * 16 + col] = acc[j];
}

// ---------------------------------------------------------------------------
// Fused GLA: per (b,h) block (1024 thr). For each 16-token strip:
//  stage q,k (fp32), v (bf16), xg1; compute e^gk in fp32; exact recurrence
//  S_t = e^{gk_t} S_{t-1} + k_t^T v_t, o_t = q_t S_t (fp32, S in regs);
//  LayerNorm(256) over o (fp32 in LDS) + silu(g) gate -> OG bf16.
__global__ __launch_bounds__(1024) void gla_fused(const float* __restrict__ QK,
                                                  const u16* __restrict__ V,
                                                  const float* __restrict__ xg1,
                                                  const float* __restrict__ W2,
                                                  const float* __restrict__ b2,
                                                  const u16* __restrict__ G,
                                                  const float* __restrict__ bg,
                                                  u16* __restrict__ OG) {
  __shared__ float W2s[16][128];   // 8KB  Wkg2 head slice
  __shared__ float b2s[128];
  __shared__ float xg1s[16][16];   // 1KB
  __shared__ float Qs[16][128];    // 8KB
  __shared__ float Ks[16][128];    // 8KB
  __shared__ float Es[16][128];    // 8KB  e^{gk}
  __shared__ u16 Vs[16][256];      // 8KB
  __shared__ float Os[16][256];    // 16KB o (pre-LN, fp32)
  const int tid = threadIdx.x;
  const int b = blockIdx.x >> 3, h = blockIdx.x & 7;
  const int dk_g = tid & 15, dv_g = tid >> 4;       // 16 dk-groups x 64 dv-groups
  const int dkb = dk_g * 8, dvb = dv_g * 4;
  const int wv = tid >> 6, lane = tid & 63;         // LN phase: wave wv <-> token
  // once: Wkg2 slice + bias
  for (int i = tid; i < 2048; i += 1024)
    W2s[i >> 7][i & 127] = W2[(size_t)(i >> 7) * 1024 + h * 128 + (i & 127)];
  if (tid < 128) b2s[tid] = b2[h * 128 + tid];
  float S[8][4] = {};
  for (int strip = 0; strip < 128; ++strip) {
    const int t0 = b * 2048 + strip * 16;
    __syncthreads();   // protect LDS reuse (prev compute/LN done)
    {   // q,k fp32: 2 floats per thread
      int c = tid * 2, row = c >> 7, col = c & 127;
      const size_t g = (size_t)(t0 + row) * 2048 + h * 128 + col;
      *(float2*)&Qs[row][col] = *(const float2*)&QK[g];
      *(float2*)&Ks[row][col] = *(const float2*)&QK[g + 1024];
    }
    {   // v bf16: 4 per thread
      int c = tid * 4, row = c >> 8, col = c & 255;
      *(ushort4*)&Vs[row][col] = *(const ushort4*)&V[(size_t)(t0 + row) * 2048 + h * 256 + col];
    }
    if (tid < 256) xg1s[tid >> 4][tid & 15] = xg1[(size_t)(t0 + (tid >> 4)) * 16 + (tid & 15)];
    __syncthreads();
    {   // e^{gk}: 2 tokens per thread
      const int d = tid & 127, tq = tid >> 7;
#pragma unroll
      for (int half = 0; half < 2; ++half) {
        const int t = tq + half * 8;
        float z = b2s[d];
#pragma unroll
        for (int kk = 0; kk < 16; ++kk) z += xg1s[t][kk] * W2s[kk][d];
        float ls = fminf(z, 0.f) - log1pf(expf(-fabsf(z)));   // stable log_sigmoid
        Es[t][d] = expf(ls * 0.0625f);                        // / NORM_GK
      }
    }
    __syncthreads();
    for (int tt = 0; tt < 16; ++tt) {   // exact recurrence
      float eg[8], qq[8], kk2[8], vv[4];
#pragma unroll
      for (int i = 0; i < 8; i += 4) {
        float4 e4 = *(const float4*)&Es[tt][dkb + i];
        eg[i] = e4.x; eg[i + 1] = e4.y; eg[i + 2] = e4.z; eg[i + 3] = e4.w;
        float4 q4 = *(const float4*)&Qs[tt][dkb + i];
        qq[i] = q4.x; qq[i + 1] = q4.y; qq[i + 2] = q4.z; qq[i + 3] = q4.w;
        float4 k4 = *(const float4*)&Ks[tt][dkb + i];
        kk2[i] = k4.x; kk2[i + 1] = k4.y; kk2[i + 2] = k4.z; kk2[i + 3] = k4.w;
      }
      ushort4 v4 = *(const ushort4*)&Vs[tt][dvb];
      vv[0] = bf2f(v4.x); vv[1] = bf2f(v4.y); vv[2] = bf2f(v4.z); vv[3] = bf2f(v4.w);
      float p[4] = {0.f, 0.f, 0.f, 0.f};
#pragma unroll
      for (int i = 0; i < 8; ++i)
#pragma unroll
        for (int j = 0; j < 4; ++j) {
          S[i][j] = eg[i] * S[i][j] + kk2[i] * vv[j];
          p[j] += qq[i] * S[i][j];
        }
#pragma unroll
      for (int j = 0; j < 4; ++j) {
        p[j] += __shfl_xor(p[j], 1, 64);
        p[j] += __shfl_xor(p[j], 2, 64);
        p[j] += __shfl_xor(p[j], 4, 64);
        p[j] += __shfl_xor(p[j], 8, 64);
      }
      if (dk_g == 0) *(float4*)&Os[tt][dvb] = make_float4(p[0], p[1], p[2], p[3]);
    }
    __syncthreads();
    {   // LayerNorm(256) + silu gate; wave wv handles token t0+wv
      float4 o4 = *(const float4*)&Os[wv][lane * 4];
      float s = o4.x + o4.y + o4.z + o4.w;
      float ss = o4.x * o4.x + o4.y * o4.y + o4.z * o4.z + o4.w * o4.w;
#pragma unroll
      for (int off = 32; off > 0; off >>= 1) {
        s += __shfl_down(s, off, 64);
        ss += __shfl_down(ss, off, 64);
      }
      s = __shfl(s, 0, 64);
      ss = __shfl(ss, 0, 64);
      float mean = s * (1.f / 256.f);
      float rstd = rsqrtf(ss * (1.f / 256.f) - mean * mean + 1e-5f);
      const size_t base = (size_t)(t0 + wv) * 2048 + h * 256 + lane * 4;
      ushort4 gv = *(const ushort4*)&G[base];
      const int bc = h * 256 + lane * 4;
      float g0 = bf2f(gv.x) + bg[bc], g1 = bf2f(gv.y) + bg[bc + 1];
      float g2 = bf2f(gv.z) + bg[bc + 2], g3 = bf2f(gv.w) + bg[bc + 3];
      ushort4 outv;
      outv.x = f2bf((o4.x - mean) * rstd * (g0 / (1.f + expf(-g0))));
      outv.y = f2bf((o4.y - mean) * rstd * (g1 / (1.f + expf(-g1))));
      outv.z = f2bf((o4.z - mean) * rstd * (g2 / (1.f + expf(-g2))));
      outv.w = f2bf((o4.w - mean) * rstd * (g3 / (1.f + expf(-g3))));
      *(ushort4*)&OG[base] = outv;
    }
  }
}

// ---------------------------------------------------------------------------
extern "C" void kernel_launch(void* const* d_in, const int* in_sizes, int n_in,
                              void* d_out, int out_size, void* d_ws, size_t ws_size,
                              hipStream_t stream) {
  (void)in_sizes; (void)n_in; (void)out_size;
  if (ws_size < 117964800ull) return;   // fail soft (round 2 proved >= 126.6MB)

  const float* x    = (const float*)d_in[0];
  const float* Wq   = (const float*)d_in[1];
  const float* Wk   = (const float*)d_in[2];
  const float* Wkg1 = (const float*)d_in[3];
  const float* Wkg2 = (const float*)d_in[4];
  const float* bkg2 = (const float*)d_in[5];
  const float* Wv   = (const float*)d_in[6];
  const float* Wg   = (const float*)d_in[7];
  const float* bg   = (const float*)d_in[8];
  const float* Wo   = (const float*)d_in[9];

  char* ws = (char*)d_ws;
  float* QK  = (float*)(ws + 0);           // 64 MiB fp32 [q|k/16]; later final-C
  u16*   V   = (u16*)(ws + 67108864);      // 32 MiB bf16
  u16*   WtA = (u16*)(ws + 100663296);     //  8 MiB hi
  u16*   WtB = (u16*)(ws + 109051904);     //  8 MiB lo
  float* xg1 = (float*)(ws + 117440512);   // 0.5 MiB
  float* Cf  = QK;                         // final GEMM C (QK dead by then)

  u16* G  = (u16*)d_out;                   // d_out [0,32Mi)
  u16* OG = (u16*)d_out + 16777216;        // d_out [32Mi,64Mi)

  dim3 tb(32, 8);

  xg1_gemm<<<dim3(128), dim3(256), 0, stream>>>(x, Wkg1, xg1);

  // [q|k] pair projection, fp32 out (Wk folded with (D/H)^-0.5 = 1/16, exact pow2)
  tpose_pair<<<dim3(32, 64), tb, 0, stream>>>(Wq, WtA,               WtB,               2048, 1024, 1.0f);
  tpose_pair<<<dim3(32, 64), tb, 0, stream>>>(Wk, WtA + 1024 * 2048, WtB + 1024 * 2048, 2048, 1024, 0.0625f);
  gemm_f32a<3, 1><<<dim3(16, 64), dim3(256), 0, stream>>>(x, WtA, WtB, (void*)QK, 8192, 2048, 2048);

  // v pair projection, bf16 out
  tpose_pair<<<dim3(64, 64), tb, 0, stream>>>(Wv, WtA, WtB, 2048, 2048, 1.0f);
  gemm_f32a<3, 0><<<dim3(16, 64), dim3(256), 0, stream>>>(x, WtA, WtB, (void*)V, 8192, 2048, 2048);

  // g projection (plain bf16 quality suffices for the gate)
  tpose_pair<<<dim3(64, 64), tb, 0, stream>>>(Wg, WtA, WtB, 2048, 2048, 1.0f);
  gemm_f32a<1, 0><<<dim3(16, 64), dim3(256), 0, stream>>>(x, WtA, WtA, (void*)G, 8192, 2048, 2048);

  // fused gk + exact scan + LayerNorm + gate
  gla_fused<<<dim3(32), dim3(1024), 0, stream>>>(QK, V, xg1, Wkg2, bkg2, G, bg, OG);

  // final projection: OG bf16 @ Wo^T -> fp32, then d2d to d_out
  tpose_pair<<<dim3(64, 64), tb, 0, stream>>>(Wo, WtA, WtB, 2048, 2048, 1.0f);
  gemm_bt<<<dim3(16, 64), dim3(256), 0, stream>>>(OG, WtA, Cf, 8192, 2048, 2048);
  hipMemcpyAsync(d_out, Cf, 67108864ull, hipMemcpyDeviceToDevice, stream);
}